// Round 1
// baseline (565.932 us; speedup 1.0000x reference)
//
#include <hip/hip_runtime.h>
#include <hip/hip_bf16.h>
#include <math.h>

#define B_ 4
#define S_ 2048
#define HID_ 768
#define NH_ 12
#define HD_ 64

typedef short bf16x8 __attribute__((ext_vector_type(8)));
typedef float f32x4 __attribute__((ext_vector_type(4)));
typedef unsigned short u16;

__device__ __forceinline__ u16 f2bf(float f) {
  union { float f; unsigned u; } x; x.f = f;
  unsigned u = x.u;
  u += 0x7FFFu + ((u >> 16) & 1u);   // round-to-nearest-even
  return (u16)(u >> 16);
}

// ---------------- cast hidden fp32 -> bf16 ----------------
__global__ void cast_x(const float* __restrict__ x, u16* __restrict__ xb, int n) {
  int i = (blockIdx.x * 256 + threadIdx.x) * 4;
  if (i >= n) return;
  float4 v = *(const float4*)(x + i);
  ushort4 o;
  o.x = f2bf(v.x); o.y = f2bf(v.y); o.z = f2bf(v.z); o.w = f2bf(v.w);
  *(ushort4*)(xb + i) = o;
}

// ------------- transpose + cast W[k][n] -> Wt[n][k] bf16 -------------
__global__ void wtrans(const float* __restrict__ Wq, const float* __restrict__ Wk,
                       const float* __restrict__ Wv, u16* __restrict__ wt) {
  const float* W = blockIdx.z == 0 ? Wq : (blockIdx.z == 1 ? Wk : Wv);
  u16* out = wt + (size_t)blockIdx.z * HID_ * HID_;
  __shared__ float t[32][33];
  int tx = threadIdx.x & 31, ty = threadIdx.x >> 5;   // 32 x 8
  int k0 = blockIdx.x * 32, n0 = blockIdx.y * 32;
#pragma unroll
  for (int i = 0; i < 4; i++)
    t[ty + 8 * i][tx] = W[(k0 + ty + 8 * i) * HID_ + n0 + tx];
  __syncthreads();
#pragma unroll
  for (int i = 0; i < 4; i++)
    out[(n0 + ty + 8 * i) * HID_ + k0 + tx] = f2bf(t[tx][ty + 8 * i]);
}

// ---------------- QKV projection GEMM ----------------
// C[m][n] = X[m][k] * W[k][n] + bias[n], written as [b, h, s, d] bf16.
__global__ __launch_bounds__(256) void qkv_gemm(
    const u16* __restrict__ xb, const u16* __restrict__ wt_all,
    const float* __restrict__ bq, const float* __restrict__ bk,
    const float* __restrict__ bv,
    u16* __restrict__ q, u16* __restrict__ k_, u16* __restrict__ v_) {
  int z = blockIdx.z;
  const u16* wt = wt_all + (size_t)z * HID_ * HID_;
  const float* bias = z == 0 ? bq : (z == 1 ? bk : bv);
  u16* out = z == 0 ? q : (z == 1 ? k_ : v_);

  int l = threadIdx.x & 63, w = threadIdx.x >> 6;
  int lr = l & 15, lg = l >> 4;
  int m0 = blockIdx.x * 128 + w * 32;
  int n0 = blockIdx.y * 64;

  f32x4 acc[2][4] = {};
  const u16* arow0 = xb + (size_t)(m0 + lr) * HID_ + 8 * lg;
  const u16* arow1 = arow0 + 16 * HID_;
  const u16* brow[4];
#pragma unroll
  for (int nt = 0; nt < 4; nt++)
    brow[nt] = wt + (size_t)(n0 + 16 * nt + lr) * HID_ + 8 * lg;

#pragma unroll 4
  for (int kk = 0; kk < HID_; kk += 32) {
    bf16x8 a0 = *(const bf16x8*)(arow0 + kk);
    bf16x8 a1 = *(const bf16x8*)(arow1 + kk);
#pragma unroll
    for (int nt = 0; nt < 4; nt++) {
      bf16x8 b = *(const bf16x8*)(brow[nt] + kk);
      acc[0][nt] = __builtin_amdgcn_mfma_f32_16x16x32_bf16(a0, b, acc[0][nt], 0, 0, 0);
      acc[1][nt] = __builtin_amdgcn_mfma_f32_16x16x32_bf16(a1, b, acc[1][nt], 0, 0, 0);
    }
  }

  int h = blockIdx.y;   // N tile == head (64 cols)
#pragma unroll
  for (int mt = 0; mt < 2; mt++)
#pragma unroll
    for (int nt = 0; nt < 4; nt++) {
      float bval = bias[n0 + 16 * nt + lr];
#pragma unroll
      for (int r = 0; r < 4; r++) {
        int m = m0 + 16 * mt + 4 * lg + r;
        int bidx = m >> 11, s = m & 2047;
        out[(((size_t)(bidx * NH_ + h)) * S_ + s) * HD_ + 16 * nt + lr] =
            f2bf(acc[mt][nt][r] + bval);
      }
    }
}

// ---------------- transpose V [b,h,s,d] -> Vt [b,h,d,s] ----------------
__global__ void vtrans(const u16* __restrict__ v, u16* __restrict__ vt) {
  __shared__ u16 t[64][65];
  int bh = blockIdx.y;
  int s0 = blockIdx.x * 64;
  int c = threadIdx.x & 63, rb = threadIdx.x >> 6;
  const u16* vin = v + ((size_t)bh * S_ + s0) * HD_;
#pragma unroll
  for (int i = 0; i < 16; i++) {
    int r = rb * 16 + i;
    t[r][c] = vin[r * HD_ + c];
  }
  __syncthreads();
  u16* vo = vt + (size_t)bh * HD_ * S_ + s0;
#pragma unroll
  for (int i = 0; i < 16; i++) {
    int d = rb * 16 + i;
    vo[d * S_ + c] = t[c][d];
  }
}

// ---------------- flash attention ----------------
// grid (S/64, B*NH), 4 waves/block, 16 q-rows per wave, KBLK=64.
__global__ __launch_bounds__(256) void attn(
    const u16* __restrict__ q, const u16* __restrict__ k_,
    const u16* __restrict__ vt, const float* __restrict__ mask,
    float* __restrict__ out) {
  int l = threadIdx.x & 63, w = threadIdx.x >> 6;
  int lr = l & 15, lg = l >> 4;
  int bh = blockIdx.y;
  int bidx = bh / NH_, h = bh % NH_;
  int q0 = blockIdx.x * 64 + w * 16;

  __shared__ u16 plds_all[4][16][72];
  u16(*plds)[72] = plds_all[w];

  const u16* qbase = q + ((size_t)bh * S_ + q0) * HD_;
  const u16* kbase = k_ + (size_t)bh * S_ * HD_;
  const u16* vtb = vt + (size_t)bh * HD_ * S_;
  const float* mrow = mask + (size_t)bidx * S_;

  bf16x8 aq0 = *(const bf16x8*)(qbase + lr * HD_ + 8 * lg);
  bf16x8 aq1 = *(const bf16x8*)(qbase + lr * HD_ + 32 + 8 * lg);

  f32x4 ctx[4] = {};
  float mrun[4], lrun[4];
#pragma unroll
  for (int r = 0; r < 4; r++) { mrun[r] = -INFINITY; lrun[r] = 0.f; }

  for (int kb = 0; kb < S_; kb += 64) {
    f32x4 sc[4] = {};
#pragma unroll
    for (int nt = 0; nt < 4; nt++) {
      const u16* kr = kbase + (size_t)(kb + 16 * nt + lr) * HD_ + 8 * lg;
      bf16x8 b0 = *(const bf16x8*)(kr);
      bf16x8 b1 = *(const bf16x8*)(kr + 32);
      sc[nt] = __builtin_amdgcn_mfma_f32_16x16x32_bf16(aq0, b0, sc[nt], 0, 0, 0);
      sc[nt] = __builtin_amdgcn_mfma_f32_16x16x32_bf16(aq1, b1, sc[nt], 0, 0, 0);
    }
    // scale + additive mask
    float mk[4];
#pragma unroll
    for (int nt = 0; nt < 4; nt++) mk[nt] = mrow[kb + 16 * nt + lr];
#pragma unroll
    for (int nt = 0; nt < 4; nt++)
#pragma unroll
      for (int r = 0; r < 4; r++)
        sc[nt][r] = sc[nt][r] * 0.125f + mk[nt];

    // online softmax: row = 4*lg + r, distributed over 16 lanes of group lg
    float scale_[4];
#pragma unroll
    for (int r = 0; r < 4; r++) {
      float v0 = fmaxf(fmaxf(sc[0][r], sc[1][r]), fmaxf(sc[2][r], sc[3][r]));
      v0 = fmaxf(v0, __shfl_xor(v0, 1));
      v0 = fmaxf(v0, __shfl_xor(v0, 2));
      v0 = fmaxf(v0, __shfl_xor(v0, 4));
      v0 = fmaxf(v0, __shfl_xor(v0, 8));
      float mnew = fmaxf(mrun[r], v0);
      scale_[r] = __expf(mrun[r] - mnew);
      mrun[r] = mnew;
    }
#pragma unroll
    for (int nt = 0; nt < 4; nt++)
#pragma unroll
      for (int r = 0; r < 4; r++)
        sc[nt][r] = __expf(sc[nt][r] - mrun[r]);
#pragma unroll
    for (int r = 0; r < 4; r++) {
      float s = sc[0][r] + sc[1][r] + sc[2][r] + sc[3][r];
      s += __shfl_xor(s, 1);
      s += __shfl_xor(s, 2);
      s += __shfl_xor(s, 4);
      s += __shfl_xor(s, 8);
      lrun[r] = lrun[r] * scale_[r] + s;
    }
#pragma unroll
    for (int nt = 0; nt < 4; nt++)
#pragma unroll
      for (int r = 0; r < 4; r++)
        ctx[nt][r] *= scale_[r];

    // P (scores layout) -> LDS -> A-fragment layout
#pragma unroll
    for (int nt = 0; nt < 4; nt++)
#pragma unroll
      for (int r = 0; r < 4; r++)
        plds[4 * lg + r][16 * nt + lr] = f2bf(sc[nt][r]);

    bf16x8 pa0 = *(const bf16x8*)(&plds[lr][8 * lg]);
    bf16x8 pa1 = *(const bf16x8*)(&plds[lr][32 + 8 * lg]);

#pragma unroll
    for (int nt = 0; nt < 4; nt++) {
      const u16* vr = vtb + (size_t)(16 * nt + lr) * S_ + kb + 8 * lg;
      bf16x8 bv0 = *(const bf16x8*)(vr);
      bf16x8 bv1 = *(const bf16x8*)(vr + 32);
      ctx[nt] = __builtin_amdgcn_mfma_f32_16x16x32_bf16(pa0, bv0, ctx[nt], 0, 0, 0);
      ctx[nt] = __builtin_amdgcn_mfma_f32_16x16x32_bf16(pa1, bv1, ctx[nt], 0, 0, 0);
    }
  }

  float* ob = out + ((size_t)bidx * S_ + q0) * HID_ + h * HD_;
#pragma unroll
  for (int nt = 0; nt < 4; nt++)
#pragma unroll
    for (int r = 0; r < 4; r++)
      ob[(size_t)(4 * lg + r) * HID_ + 16 * nt + lr] = ctx[nt][r] / lrun[r];
}

extern "C" void kernel_launch(void* const* d_in, const int* in_sizes, int n_in,
                              void* d_out, int out_size, void* d_ws, size_t ws_size,
                              hipStream_t stream) {
  const float* x    = (const float*)d_in[0];
  const float* mask = (const float*)d_in[1];
  const float* Wq   = (const float*)d_in[2];
  const float* bq   = (const float*)d_in[3];
  const float* Wk   = (const float*)d_in[4];
  const float* bk   = (const float*)d_in[5];
  const float* Wv   = (const float*)d_in[6];
  const float* bv   = (const float*)d_in[7];
  float* out = (float*)d_out;

  char* ws = (char*)d_ws;
  const size_t SZ_X  = (size_t)B_ * S_ * HID_ * 2;        // 12,582,912
  const size_t SZ_W  = (size_t)3 * HID_ * HID_ * 2;       //  3,538,944
  u16* xb = (u16*)ws;
  u16* wt = (u16*)(ws + SZ_X);
  u16* q  = (u16*)(ws + SZ_X + SZ_W);
  u16* k  = (u16*)(ws + SZ_X + SZ_W + SZ_X);
  u16* v  = (u16*)(ws + SZ_X + SZ_W + 2 * SZ_X);
  u16* vt = (u16*)(ws + SZ_X + SZ_W + 3 * SZ_X);

  int n = B_ * S_ * HID_;
  hipLaunchKernelGGL(cast_x, dim3(n / 1024), dim3(256), 0, stream, x, xb, n);
  hipLaunchKernelGGL(wtrans, dim3(24, 24, 3), dim3(256), 0, stream, Wq, Wk, Wv, wt);
  hipLaunchKernelGGL(qkv_gemm, dim3(64, 12, 3), dim3(256), 0, stream,
                     xb, wt, bq, bk, bv, q, k, v);
  hipLaunchKernelGGL(vtrans, dim3(32, 48), dim3(256), 0, stream, v, vt);
  hipLaunchKernelGGL(attn, dim3(32, 48), dim3(256), 0, stream, q, k, vt, mask, out);
}

// Round 2
// 356.311 us; speedup vs baseline: 1.5883x; 1.5883x over previous
//
#include <hip/hip_runtime.h>
#include <hip/hip_bf16.h>
#include <math.h>

#define B_ 4
#define S_ 2048
#define HID_ 768
#define NH_ 12
#define HD_ 64

typedef short bf16x8 __attribute__((ext_vector_type(8)));
typedef float f32x4 __attribute__((ext_vector_type(4)));
typedef unsigned short u16;

__device__ __forceinline__ u16 f2bf(float f) {
  union { float f; unsigned u; } x; x.f = f;
  unsigned u = x.u;
  u += 0x7FFFu + ((u >> 16) & 1u);   // round-to-nearest-even
  return (u16)(u >> 16);
}

// ---------------- cast hidden fp32 -> bf16 ----------------
__global__ void cast_x(const float* __restrict__ x, u16* __restrict__ xb, int n) {
  int i = (blockIdx.x * 256 + threadIdx.x) * 4;
  if (i >= n) return;
  float4 v = *(const float4*)(x + i);
  ushort4 o;
  o.x = f2bf(v.x); o.y = f2bf(v.y); o.z = f2bf(v.z); o.w = f2bf(v.w);
  *(ushort4*)(xb + i) = o;
}

// ------------- transpose + cast W[k][n] -> Wt[n][k] bf16 -------------
__global__ void wtrans(const float* __restrict__ Wq, const float* __restrict__ Wk,
                       const float* __restrict__ Wv, u16* __restrict__ wt) {
  const float* W = blockIdx.z == 0 ? Wq : (blockIdx.z == 1 ? Wk : Wv);
  u16* out = wt + (size_t)blockIdx.z * HID_ * HID_;
  __shared__ float t[32][33];
  int tx = threadIdx.x & 31, ty = threadIdx.x >> 5;   // 32 x 8
  int k0 = blockIdx.x * 32, n0 = blockIdx.y * 32;
#pragma unroll
  for (int i = 0; i < 4; i++)
    t[ty + 8 * i][tx] = W[(k0 + ty + 8 * i) * HID_ + n0 + tx];
  __syncthreads();
#pragma unroll
  for (int i = 0; i < 4; i++)
    out[(n0 + ty + 8 * i) * HID_ + k0 + tx] = f2bf(t[tx][ty + 8 * i]);
}

// ---------------- QKV projection GEMM ----------------
__global__ __launch_bounds__(256) void qkv_gemm(
    const u16* __restrict__ xb, const u16* __restrict__ wt_all,
    const float* __restrict__ bq, const float* __restrict__ bk,
    const float* __restrict__ bv,
    u16* __restrict__ q, u16* __restrict__ k_, u16* __restrict__ v_) {
  int z = blockIdx.z;
  const u16* wt = wt_all + (size_t)z * HID_ * HID_;
  const float* bias = z == 0 ? bq : (z == 1 ? bk : bv);
  u16* out = z == 0 ? q : (z == 1 ? k_ : v_);

  int l = threadIdx.x & 63, w = threadIdx.x >> 6;
  int lr = l & 15, lg = l >> 4;
  int m0 = blockIdx.x * 128 + w * 32;
  int n0 = blockIdx.y * 64;

  f32x4 acc[2][4] = {};
  const u16* arow0 = xb + (size_t)(m0 + lr) * HID_ + 8 * lg;
  const u16* arow1 = arow0 + 16 * HID_;
  const u16* brow[4];
#pragma unroll
  for (int nt = 0; nt < 4; nt++)
    brow[nt] = wt + (size_t)(n0 + 16 * nt + lr) * HID_ + 8 * lg;

#pragma unroll 4
  for (int kk = 0; kk < HID_; kk += 32) {
    bf16x8 a0 = *(const bf16x8*)(arow0 + kk);
    bf16x8 a1 = *(const bf16x8*)(arow1 + kk);
#pragma unroll
    for (int nt = 0; nt < 4; nt++) {
      bf16x8 b = *(const bf16x8*)(brow[nt] + kk);
      acc[0][nt] = __builtin_amdgcn_mfma_f32_16x16x32_bf16(a0, b, acc[0][nt], 0, 0, 0);
      acc[1][nt] = __builtin_amdgcn_mfma_f32_16x16x32_bf16(a1, b, acc[1][nt], 0, 0, 0);
    }
  }

  int h = blockIdx.y;
#pragma unroll
  for (int mt = 0; mt < 2; mt++)
#pragma unroll
    for (int nt = 0; nt < 4; nt++) {
      float bval = bias[n0 + 16 * nt + lr];
#pragma unroll
      for (int r = 0; r < 4; r++) {
        int m = m0 + 16 * mt + 4 * lg + r;
        int bidx = m >> 11, s = m & 2047;
        out[(((size_t)(bidx * NH_ + h)) * S_ + s) * HD_ + 16 * nt + lr] =
            f2bf(acc[mt][nt][r] + bval);
      }
    }
}

// ---------------- transpose V [b,h,s,d] -> Vt [b,h,d,s] ----------------
__global__ void vtrans(const u16* __restrict__ v, u16* __restrict__ vt) {
  __shared__ u16 t[64][65];
  int bh = blockIdx.y;
  int s0 = blockIdx.x * 64;
  int c = threadIdx.x & 63, rb = threadIdx.x >> 6;
  const u16* vin = v + ((size_t)bh * S_ + s0) * HD_;
#pragma unroll
  for (int i = 0; i < 16; i++) {
    int r = rb * 16 + i;
    t[r][c] = vin[r * HD_ + c];
  }
  __syncthreads();
  u16* vo = vt + (size_t)bh * HD_ * S_ + s0;
#pragma unroll
  for (int i = 0; i < 16; i++) {
    int d = rb * 16 + i;
    vo[d * S_ + c] = t[c][d];
  }
}

// ---------------- flash attention, swapped-QK layout ----------------
// grid (S/128, B*NH), 4 waves/block, 32 q-rows per wave (2 q-tiles), KBLK=64.
// QK^T computed as mfma(K, Q) -> D[kv][q]: each lane owns ONE q-row (q = lane&15)
// with kv = 16*nt + 4*lg + r in registers => softmax is in-lane + 2 shuffles.
__global__ __launch_bounds__(256) void attn2(
    const u16* __restrict__ q, const u16* __restrict__ k_,
    const u16* __restrict__ vt, const float* __restrict__ mask,
    float* __restrict__ out) {
  int l = threadIdx.x & 63, w = threadIdx.x >> 6;
  int lr = l & 15, lg = l >> 4;
  int bh = blockIdx.y;
  int bidx = bh / NH_, h = bh % NH_;
  int q0 = blockIdx.x * 128 + w * 32;

  // per-wave scratch: P^T tile u16[32][72] (4608B) OR f32[16][68] epilogue (4352B)
  __shared__ __align__(16) char smem[4][4608];
  u16(*plds)[72] = (u16(*)[72])smem[w];
  float* ct = (float*)smem[w];

  const u16* qbase = q + ((size_t)bh * S_ + q0) * HD_;
  const u16* kbase = k_ + (size_t)bh * S_ * HD_;
  const u16* vtb = vt + (size_t)bh * HD_ * S_;
  const float* mrow = mask + (size_t)bidx * S_;

  bf16x8 aq[2][2];
#pragma unroll
  for (int qt = 0; qt < 2; qt++)
#pragma unroll
    for (int h2 = 0; h2 < 2; h2++)
      aq[qt][h2] = *(const bf16x8*)(qbase + (size_t)(16 * qt + lr) * HD_ + 8 * lg + 32 * h2);

  f32x4 ctx[2][4] = {};
  float mrun[2] = {-INFINITY, -INFINITY};
  float lrun[2] = {0.f, 0.f};

  for (int kb = 0; kb < S_; kb += 64) {
    // K fragments (A-operand: row = kv)
    bf16x8 kf[4][2];
#pragma unroll
    for (int nt = 0; nt < 4; nt++) {
      const u16* kr = kbase + (size_t)(kb + 16 * nt + lr) * HD_ + 8 * lg;
      kf[nt][0] = *(const bf16x8*)(kr);
      kf[nt][1] = *(const bf16x8*)(kr + 32);
    }

    // QK^T swapped: D[kv][q]
    f32x4 sc[2][4] = {};
#pragma unroll
    for (int nt = 0; nt < 4; nt++)
#pragma unroll
      for (int qt = 0; qt < 2; qt++) {
        sc[qt][nt] = __builtin_amdgcn_mfma_f32_16x16x32_bf16(kf[nt][0], aq[qt][0], sc[qt][nt], 0, 0, 0);
        sc[qt][nt] = __builtin_amdgcn_mfma_f32_16x16x32_bf16(kf[nt][1], aq[qt][1], sc[qt][nt], 0, 0, 0);
      }

    // issue V^T fragment loads early (independent of softmax)
    bf16x8 vf[4][2];
#pragma unroll
    for (int nt = 0; nt < 4; nt++) {
      const u16* vr = vtb + (size_t)(16 * nt + lr) * S_ + kb + 8 * lg;
      vf[nt][0] = *(const bf16x8*)(vr);
      vf[nt][1] = *(const bf16x8*)(vr + 32);
    }

    // mask values for kv = kb + 16*nt + 4*lg + r (vectorized)
    f32x4 mk[4];
#pragma unroll
    for (int nt = 0; nt < 4; nt++)
      mk[nt] = *(const f32x4*)(mrow + kb + 16 * nt + 4 * lg);

#pragma unroll
    for (int qt = 0; qt < 2; qt++) {
      // scale + mask
#pragma unroll
      for (int nt = 0; nt < 4; nt++)
#pragma unroll
        for (int r = 0; r < 4; r++)
          sc[qt][nt][r] = sc[qt][nt][r] * 0.125f + mk[nt][r];

      // in-lane max over 16, then reduce across the 4 lane-groups
      float m0_ = fmaxf(fmaxf(sc[qt][0][0], sc[qt][0][1]), fmaxf(sc[qt][0][2], sc[qt][0][3]));
      float m1_ = fmaxf(fmaxf(sc[qt][1][0], sc[qt][1][1]), fmaxf(sc[qt][1][2], sc[qt][1][3]));
      float m2_ = fmaxf(fmaxf(sc[qt][2][0], sc[qt][2][1]), fmaxf(sc[qt][2][2], sc[qt][2][3]));
      float m3_ = fmaxf(fmaxf(sc[qt][3][0], sc[qt][3][1]), fmaxf(sc[qt][3][2], sc[qt][3][3]));
      float vmax = fmaxf(fmaxf(m0_, m1_), fmaxf(m2_, m3_));
      vmax = fmaxf(vmax, __shfl_xor(vmax, 16));
      vmax = fmaxf(vmax, __shfl_xor(vmax, 32));

      float mnew = fmaxf(mrun[qt], vmax);
      float scl = __expf(mrun[qt] - mnew);
      mrun[qt] = mnew;

      // exp + sum
      float psum = 0.f;
#pragma unroll
      for (int nt = 0; nt < 4; nt++)
#pragma unroll
        for (int r = 0; r < 4; r++) {
          sc[qt][nt][r] = __expf(sc[qt][nt][r] - mnew);
          psum += sc[qt][nt][r];
        }
      psum += __shfl_xor(psum, 16);
      psum += __shfl_xor(psum, 32);
      lrun[qt] = lrun[qt] * scl + psum;

#pragma unroll
      for (int nt = 0; nt < 4; nt++)
        ctx[qt][nt] *= scl;

      // P^T to LDS: row = q (16*qt + lr), cols kv = 16*nt + 4*lg + r  (b64 writes)
#pragma unroll
      for (int nt = 0; nt < 4; nt++) {
        ushort4 pk;
        pk.x = f2bf(sc[qt][nt][0]);
        pk.y = f2bf(sc[qt][nt][1]);
        pk.z = f2bf(sc[qt][nt][2]);
        pk.w = f2bf(sc[qt][nt][3]);
        *(ushort4*)(&plds[16 * qt + lr][16 * nt + 4 * lg]) = pk;
      }
    }

    // B-fragments of P^T: lane needs P^T[kv = 32*h2 + 8*lg + j][q = lr]
    bf16x8 pb[2][2];
#pragma unroll
    for (int qt = 0; qt < 2; qt++)
#pragma unroll
      for (int h2 = 0; h2 < 2; h2++)
        pb[qt][h2] = *(const bf16x8*)(&plds[16 * qt + lr][32 * h2 + 8 * lg]);

    // PV: ctx^T[d][q] += V^T[d][kv] * P^T[kv][q]
#pragma unroll
    for (int nt = 0; nt < 4; nt++)
#pragma unroll
      for (int qt = 0; qt < 2; qt++) {
        ctx[qt][nt] = __builtin_amdgcn_mfma_f32_16x16x32_bf16(vf[nt][0], pb[qt][0], ctx[qt][nt], 0, 0, 0);
        ctx[qt][nt] = __builtin_amdgcn_mfma_f32_16x16x32_bf16(vf[nt][1], pb[qt][1], ctx[qt][nt], 0, 0, 0);
      }
  }

  // epilogue: ctx^T[d][q] -> LDS -> coalesced row stores
#pragma unroll
  for (int qt = 0; qt < 2; qt++) {
    float inv = 1.f / lrun[qt];
#pragma unroll
    for (int nt = 0; nt < 4; nt++) {
      f32x4 vv = ctx[qt][nt] * inv;
      *(f32x4*)(ct + lr * 68 + 16 * nt + 4 * lg) = vv;   // ct[q=lr][d]
    }
    float* ob = out + ((size_t)bidx * S_ + q0 + 16 * qt) * HID_ + h * HD_;
#pragma unroll
    for (int i = 0; i < 16; i++)
      ob[(size_t)i * HID_ + l] = ct[i * 68 + l];
  }
}

extern "C" void kernel_launch(void* const* d_in, const int* in_sizes, int n_in,
                              void* d_out, int out_size, void* d_ws, size_t ws_size,
                              hipStream_t stream) {
  const float* x    = (const float*)d_in[0];
  const float* mask = (const float*)d_in[1];
  const float* Wq   = (const float*)d_in[2];
  const float* bq   = (const float*)d_in[3];
  const float* Wk   = (const float*)d_in[4];
  const float* bk   = (const float*)d_in[5];
  const float* Wv   = (const float*)d_in[6];
  const float* bv   = (const float*)d_in[7];
  float* out = (float*)d_out;

  char* ws = (char*)d_ws;
  const size_t SZ_X  = (size_t)B_ * S_ * HID_ * 2;
  const size_t SZ_W  = (size_t)3 * HID_ * HID_ * 2;
  u16* xb = (u16*)ws;
  u16* wt = (u16*)(ws + SZ_X);
  u16* q  = (u16*)(ws + SZ_X + SZ_W);
  u16* k  = (u16*)(ws + SZ_X + SZ_W + SZ_X);
  u16* v  = (u16*)(ws + SZ_X + SZ_W + 2 * SZ_X);
  u16* vt = (u16*)(ws + SZ_X + SZ_W + 3 * SZ_X);

  int n = B_ * S_ * HID_;
  hipLaunchKernelGGL(cast_x, dim3(n / 1024), dim3(256), 0, stream, x, xb, n);
  hipLaunchKernelGGL(wtrans, dim3(24, 24, 3), dim3(256), 0, stream, Wq, Wk, Wv, wt);
  hipLaunchKernelGGL(qkv_gemm, dim3(64, 12, 3), dim3(256), 0, stream,
                     xb, wt, bq, bk, bv, q, k, v);
  hipLaunchKernelGGL(vtrans, dim3(32, 48), dim3(256), 0, stream, v, vt);
  hipLaunchKernelGGL(attn2, dim3(16, 48), dim3(256), 0, stream, q, k, vt, mask, out);
}